// Round 1
// baseline (653.188 us; speedup 1.0000x reference)
//
#include <hip/hip_runtime.h>
#include <hip/hip_bf16.h>

#define T_TOK 2048
#define H_DIM 2048
#define E_NUM 16
#define I_DIM 768

typedef __bf16 bf16;
typedef __bf16 bf16x4 __attribute__((ext_vector_type(4)));
typedef __bf16 bf16x8 __attribute__((ext_vector_type(8)));
typedef float f32x4 __attribute__((ext_vector_type(4)));

// ---------------- Router: fp64-accurate logits, top-2, bucket fill ----------
__global__ __launch_bounds__(256) void router_kernel(
    const float* __restrict__ x, const float* __restrict__ gw,
    float* __restrict__ logits, int* __restrict__ cnt,
    int* __restrict__ tok_list, float* __restrict__ wgt_list)
{
    int t = blockIdx.x;
    int tid = threadIdx.x;
    __shared__ double red[E_NUM][256];
    double part[E_NUM];
#pragma unroll
    for (int e = 0; e < E_NUM; ++e) part[e] = 0.0;
    for (int h = tid; h < H_DIM; h += 256) {
        double xv = (double)x[(size_t)t * H_DIM + h];
#pragma unroll
        for (int e = 0; e < E_NUM; ++e)
            part[e] += xv * (double)gw[e * H_DIM + h];
    }
#pragma unroll
    for (int e = 0; e < E_NUM; ++e) red[e][tid] = part[e];
    __syncthreads();
    for (int s = 128; s > 0; s >>= 1) {
        if (tid < s) {
#pragma unroll
            for (int e = 0; e < E_NUM; ++e) red[e][tid] += red[e][tid + s];
        }
        __syncthreads();
    }
    __shared__ float lg[E_NUM];
    if (tid < E_NUM) {
        float v = (float)red[tid][0];
        lg[tid] = v;
        logits[(size_t)t * E_NUM + tid] = v;
    }
    __syncthreads();
    if (tid == 0) {
        int i0 = 0; float v0 = lg[0];
#pragma unroll
        for (int e = 1; e < E_NUM; ++e) if (lg[e] > v0) { v0 = lg[e]; i0 = e; }
        int i1 = -1; float v1 = -3.4e38f;
#pragma unroll
        for (int e = 0; e < E_NUM; ++e) if (e != i0 && lg[e] > v1) { v1 = lg[e]; i1 = e; }
        // normalized top-2 weights: softmax denom cancels
        float w0 = 1.0f / (1.0f + __expf(v1 - v0));
        float w1 = 1.0f - w0;
        int p0 = atomicAdd(&cnt[i0], 1);
        tok_list[i0 * T_TOK + p0] = t; wgt_list[i0 * T_TOK + p0] = w0;
        int p1 = atomicAdd(&cnt[i1], 1);
        tok_list[i1 * T_TOK + p1] = t; wgt_list[i1 * T_TOK + p1] = w1;
    }
}

// ---------------- Offsets scan (16 values) ----------------------------------
__global__ void scan_kernel(const int* __restrict__ cnt, int* __restrict__ offs)
{
    if (threadIdx.x == 0) {
        int o = 0;
        for (int e = 0; e < E_NUM; ++e) { offs[e] = o; o += cnt[e]; }
    }
}

// ---------------- Grouped gate_up GEMM + SwiGLU ------------------------------
// Tile: M=128 tokens x 64 I-columns (computes both g and u => N=128 weight rows)
#define TM 128
#define BK 64
#define LDK 72  // +8 bf16 pad to break LDS bank conflicts

__global__ __launch_bounds__(256) void gateup_kernel(
    const float* __restrict__ x, const float* __restrict__ gup,
    const int* __restrict__ cnt, const int* __restrict__ offs,
    const int* __restrict__ tok_list, bf16* __restrict__ hbuf)
{
    int e = blockIdx.z;
    int count = cnt[e];
    int row0 = blockIdx.y * TM;
    if (row0 >= count) return;
    int i0 = blockIdx.x * 64;
    const float* W = gup + (size_t)e * (2 * I_DIM) * H_DIM;
    int hoff = offs[e];

    __shared__ __align__(16) bf16 As[TM][LDK];
    __shared__ __align__(16) bf16 Bs[128][LDK];
    __shared__ int toks[TM];

    int tid = threadIdx.x;
    if (tid < TM) {
        int r = row0 + tid;
        if (r > count - 1) r = count - 1;
        toks[tid] = tok_list[e * T_TOK + r];
    }
    __syncthreads();

    int lane = tid & 63, wid = tid >> 6;
    int wm = wid >> 1, wn = wid & 1;        // wave quadrant: rows 64*wm, i-cols 32*wn
    int la = lane & 15, lq = lane >> 4;

    f32x4 accg[4][2], accu[4][2];
#pragma unroll
    for (int a = 0; a < 4; ++a)
#pragma unroll
        for (int b = 0; b < 2; ++b) {
            accg[a][b] = (f32x4){0.f, 0.f, 0.f, 0.f};
            accu[a][b] = (f32x4){0.f, 0.f, 0.f, 0.f};
        }

    int ar = tid >> 1;            // 0..127: row handled by this thread (A and B)
    int ac = (tid & 1) * 32;      // col half
    const float* xrow = x + (size_t)toks[ar] * H_DIM;
    int brow = (ar < 64) ? (i0 + ar) : (768 + i0 + (ar - 64));  // g rows then u rows
    const float* wrow = W + (size_t)brow * H_DIM;

    for (int k0 = 0; k0 < H_DIM; k0 += BK) {
        // stage A (tokens) fp32->bf16
#pragma unroll
        for (int j = 0; j < 8; ++j) {
            float4 v = *(const float4*)(xrow + k0 + ac + 4 * j);
            bf16x4 b = { (bf16)v.x, (bf16)v.y, (bf16)v.z, (bf16)v.w };
            *(bf16x4*)&As[ar][ac + 4 * j] = b;
        }
        // stage B (gate_up weights) fp32->bf16
#pragma unroll
        for (int j = 0; j < 8; ++j) {
            float4 v = *(const float4*)(wrow + k0 + ac + 4 * j);
            bf16x4 b = { (bf16)v.x, (bf16)v.y, (bf16)v.z, (bf16)v.w };
            *(bf16x4*)&Bs[ar][ac + 4 * j] = b;
        }
        __syncthreads();
#pragma unroll
        for (int ks = 0; ks < BK; ks += 32) {
            bf16x8 af[4], bg[2], bu[2];
#pragma unroll
            for (int mt = 0; mt < 4; ++mt)
                af[mt] = *(const bf16x8*)&As[64 * wm + 16 * mt + la][ks + lq * 8];
#pragma unroll
            for (int nt = 0; nt < 2; ++nt) {
                bg[nt] = *(const bf16x8*)&Bs[32 * wn + 16 * nt + la][ks + lq * 8];
                bu[nt] = *(const bf16x8*)&Bs[64 + 32 * wn + 16 * nt + la][ks + lq * 8];
            }
#pragma unroll
            for (int mt = 0; mt < 4; ++mt)
#pragma unroll
                for (int nt = 0; nt < 2; ++nt) {
                    accg[mt][nt] = __builtin_amdgcn_mfma_f32_16x16x32_bf16(af[mt], bg[nt], accg[mt][nt], 0, 0, 0);
                    accu[mt][nt] = __builtin_amdgcn_mfma_f32_16x16x32_bf16(af[mt], bu[nt], accu[mt][nt], 0, 0, 0);
                }
        }
        __syncthreads();
    }
    // epilogue: h = silu(g) * u, store bf16
#pragma unroll
    for (int mt = 0; mt < 4; ++mt)
#pragma unroll
        for (int nt = 0; nt < 2; ++nt)
#pragma unroll
            for (int r = 0; r < 4; ++r) {
                int lrow = 64 * wm + 16 * mt + lq * 4 + r;
                if (row0 + lrow < count) {
                    int col = i0 + 32 * wn + 16 * nt + la;
                    float g = accg[mt][nt][r], u = accu[mt][nt][r];
                    float hv = (g / (1.0f + __expf(-g))) * u;
                    hbuf[(size_t)(hoff + row0 + lrow) * I_DIM + col] = (bf16)hv;
                }
            }
}

// ---------------- Grouped down GEMM + weighted scatter -----------------------
__global__ __launch_bounds__(256) void down_kernel(
    const float* __restrict__ dw, const bf16* __restrict__ hbuf,
    const int* __restrict__ cnt, const int* __restrict__ offs,
    const int* __restrict__ tok_list, const float* __restrict__ wgt_list,
    float* __restrict__ out)
{
    int e = blockIdx.z;
    int count = cnt[e];
    int row0 = blockIdx.y * TM;
    if (row0 >= count) return;
    int n0 = blockIdx.x * 128;
    const float* W = dw + (size_t)e * H_DIM * I_DIM;
    int hoff = offs[e];

    __shared__ __align__(16) bf16 As[TM][LDK];
    __shared__ __align__(16) bf16 Bs[128][LDK];
    __shared__ int toks[TM];
    __shared__ float wgts[TM];

    int tid = threadIdx.x;
    if (tid < TM) {
        int r = row0 + tid;
        if (r > count - 1) r = count - 1;
        toks[tid] = tok_list[e * T_TOK + r];
        wgts[tid] = wgt_list[e * T_TOK + r];
    }
    __syncthreads();

    int lane = tid & 63, wid = tid >> 6;
    int wm = wid >> 1, wn = wid & 1;
    int la = lane & 15, lq = lane >> 4;

    f32x4 acc[4][4];
#pragma unroll
    for (int a = 0; a < 4; ++a)
#pragma unroll
        for (int b = 0; b < 4; ++b) acc[a][b] = (f32x4){0.f, 0.f, 0.f, 0.f};

    int ar = tid >> 1;
    int ac = (tid & 1) * 32;
    int arow = row0 + ar; if (arow > count - 1) arow = count - 1;
    const bf16* hrow = hbuf + (size_t)(hoff + arow) * I_DIM;
    const float* wrow = W + (size_t)(n0 + ar) * I_DIM;

    for (int k0 = 0; k0 < I_DIM; k0 += BK) {
        // stage A: bf16 copy 16B-wide
#pragma unroll
        for (int j = 0; j < 4; ++j) {
            bf16x8 v = *(const bf16x8*)(hrow + k0 + ac + 8 * j);
            *(bf16x8*)&As[ar][ac + 8 * j] = v;
        }
        // stage B: down weights fp32->bf16
#pragma unroll
        for (int j = 0; j < 8; ++j) {
            float4 v = *(const float4*)(wrow + k0 + ac + 4 * j);
            bf16x4 b = { (bf16)v.x, (bf16)v.y, (bf16)v.z, (bf16)v.w };
            *(bf16x4*)&Bs[ar][ac + 4 * j] = b;
        }
        __syncthreads();
#pragma unroll
        for (int ks = 0; ks < BK; ks += 32) {
            bf16x8 af[4], bb[4];
#pragma unroll
            for (int mt = 0; mt < 4; ++mt)
                af[mt] = *(const bf16x8*)&As[64 * wm + 16 * mt + la][ks + lq * 8];
#pragma unroll
            for (int nt = 0; nt < 4; ++nt)
                bb[nt] = *(const bf16x8*)&Bs[64 * wn + 16 * nt + la][ks + lq * 8];
#pragma unroll
            for (int mt = 0; mt < 4; ++mt)
#pragma unroll
                for (int nt = 0; nt < 4; ++nt)
                    acc[mt][nt] = __builtin_amdgcn_mfma_f32_16x16x32_bf16(af[mt], bb[nt], acc[mt][nt], 0, 0, 0);
        }
        __syncthreads();
    }
#pragma unroll
    for (int mt = 0; mt < 4; ++mt)
#pragma unroll
        for (int nt = 0; nt < 4; ++nt)
#pragma unroll
            for (int r = 0; r < 4; ++r) {
                int lrow = 64 * wm + 16 * mt + lq * 4 + r;
                if (row0 + lrow < count) {
                    int col = n0 + 64 * wn + 16 * nt + la;
                    atomicAdd(&out[(size_t)toks[lrow] * H_DIM + col],
                              wgts[lrow] * acc[mt][nt][r]);
                }
            }
}

// ---------------- Launch -----------------------------------------------------
extern "C" void kernel_launch(void* const* d_in, const int* in_sizes, int n_in,
                              void* d_out, int out_size, void* d_ws, size_t ws_size,
                              hipStream_t stream)
{
    const float* x   = (const float*)d_in[0];
    const float* gw  = (const float*)d_in[1];
    const float* gup = (const float*)d_in[2];
    const float* dw  = (const float*)d_in[3];
    float* out = (float*)d_out;
    float* logits = out + (size_t)T_TOK * H_DIM;

    char* ws = (char*)d_ws;
    int*   cnt      = (int*)(ws + 0);
    int*   offs     = (int*)(ws + 128);
    int*   tok_list = (int*)(ws + 256);                       // int[E*T] = 128 KiB
    float* wgt_list = (float*)(ws + 256 + 131072);            // float[E*T] = 128 KiB
    bf16*  hbuf     = (bf16*)(ws + 256 + 262144);             // bf16[2T * I] = 6 MiB

    hipMemsetAsync(cnt, 0, 128, stream);
    hipMemsetAsync(out, 0, (size_t)T_TOK * H_DIM * sizeof(float), stream);

    router_kernel<<<T_TOK, 256, 0, stream>>>(x, gw, logits, cnt, tok_list, wgt_list);
    scan_kernel<<<1, 64, 0, stream>>>(cnt, offs);
    gateup_kernel<<<dim3(I_DIM / 64, T_TOK / TM, E_NUM), 256, 0, stream>>>(
        x, gup, cnt, offs, tok_list, hbuf);
    down_kernel<<<dim3(H_DIM / 128, T_TOK / TM, E_NUM), 256, 0, stream>>>(
        dw, hbuf, cnt, offs, tok_list, wgt_list, out);
}

// Round 2
// 555.506 us; speedup vs baseline: 1.1758x; 1.1758x over previous
//
#include <hip/hip_runtime.h>
#include <hip/hip_bf16.h>
#include <stdint.h>

#define T_TOK 2048
#define H_DIM 2048
#define E_NUM 16
#define I_DIM 768

typedef __bf16 bf16;
typedef __bf16 bf16x8 __attribute__((ext_vector_type(8)));
typedef float f32x4 __attribute__((ext_vector_type(4)));

__device__ __forceinline__ void async_cp16(bf16* l, const bf16* g) {
    __builtin_amdgcn_global_load_lds(
        (const __attribute__((address_space(1))) void*)g,
        (__attribute__((address_space(3))) void*)l, 16, 0, 0);
}

// ---------------- Router: fp64-accurate logits, top-2, bucket fill, x->bf16 --
__global__ __launch_bounds__(256) void router_kernel(
    const float* __restrict__ x, const float* __restrict__ gw,
    float* __restrict__ logits, int* __restrict__ cnt,
    int* __restrict__ tok_list, float* __restrict__ wgt_list,
    bf16* __restrict__ xb)
{
    int t = blockIdx.x;
    int tid = threadIdx.x;
    __shared__ double red[E_NUM][256];
    double part[E_NUM];
#pragma unroll
    for (int e = 0; e < E_NUM; ++e) part[e] = 0.0;
    for (int h = tid; h < H_DIM; h += 256) {
        float xf = x[(size_t)t * H_DIM + h];
        xb[(size_t)t * H_DIM + h] = (bf16)xf;
        double xv = (double)xf;
#pragma unroll
        for (int e = 0; e < E_NUM; ++e)
            part[e] += xv * (double)gw[e * H_DIM + h];
    }
#pragma unroll
    for (int e = 0; e < E_NUM; ++e) red[e][tid] = part[e];
    __syncthreads();
    for (int s = 128; s > 0; s >>= 1) {
        if (tid < s) {
#pragma unroll
            for (int e = 0; e < E_NUM; ++e) red[e][tid] += red[e][tid + s];
        }
        __syncthreads();
    }
    __shared__ float lg[E_NUM];
    if (tid < E_NUM) {
        float v = (float)red[tid][0];
        lg[tid] = v;
        logits[(size_t)t * E_NUM + tid] = v;
    }
    __syncthreads();
    if (tid == 0) {
        int i0 = 0; float v0 = lg[0];
#pragma unroll
        for (int e = 1; e < E_NUM; ++e) if (lg[e] > v0) { v0 = lg[e]; i0 = e; }
        int i1 = -1; float v1 = -3.4e38f;
#pragma unroll
        for (int e = 0; e < E_NUM; ++e) if (e != i0 && lg[e] > v1) { v1 = lg[e]; i1 = e; }
        float w0 = 1.0f / (1.0f + __expf(v1 - v0));
        float w1 = 1.0f - w0;
        int p0 = atomicAdd(&cnt[i0], 1);
        tok_list[i0 * T_TOK + p0] = t; wgt_list[i0 * T_TOK + p0] = w0;
        int p1 = atomicAdd(&cnt[i1], 1);
        tok_list[i1 * T_TOK + p1] = t; wgt_list[i1 * T_TOK + p1] = w1;
    }
}

// ---------------- Offsets scan (16 values) ----------------------------------
__global__ void scan_kernel(const int* __restrict__ cnt, int* __restrict__ offs)
{
    if (threadIdx.x == 0) {
        int o = 0;
        for (int e = 0; e < E_NUM; ++e) { offs[e] = o; o += cnt[e]; }
    }
}

// ---------------- Weight fp32 -> bf16 convert --------------------------------
__global__ __launch_bounds__(256) void convert_kernel(
    const float* __restrict__ gup, const float* __restrict__ dwn,
    bf16* __restrict__ gub, bf16* __restrict__ dwb)
{
    const size_t NG = (size_t)E_NUM * 2 * I_DIM * H_DIM / 8;  // 6,291,456 chunks
    const size_t ND = (size_t)E_NUM * H_DIM * I_DIM / 8;      // 3,145,728 chunks
    size_t stride = (size_t)gridDim.x * 256;
    for (size_t c = (size_t)blockIdx.x * 256 + threadIdx.x; c < NG + ND; c += stride) {
        const float* s; bf16* d; size_t off;
        if (c < NG) { s = gup; d = gub; off = c * 8; }
        else        { s = dwn; d = dwb; off = (c - NG) * 8; }
        float4 a = *(const float4*)(s + off);
        float4 b = *(const float4*)(s + off + 4);
        bf16x8 v = { (bf16)a.x, (bf16)a.y, (bf16)a.z, (bf16)a.w,
                     (bf16)b.x, (bf16)b.y, (bf16)b.z, (bf16)b.w };
        *(bf16x8*)(d + off) = v;
    }
}

// ---------------- Grouped gate_up GEMM + SwiGLU ------------------------------
// Tile: M=64 tokens x 64 i-cols (128 weight rows: groups of 32 g / 32 u).
// LDS XOR-swizzle: chunk (row r, col-chunk c8) stored at slot (c8 ^ (r&7)).
__global__ __launch_bounds__(256, 4) void gateup_kernel(
    const bf16* __restrict__ xb, const bf16* __restrict__ gub,
    const int* __restrict__ cnt, const int* __restrict__ offs,
    const int* __restrict__ tok_list, bf16* __restrict__ hbuf)
{
    const int e = blockIdx.z;
    const int count = cnt[e];
    const int row0 = blockIdx.y * 64;
    if (row0 >= count) return;
    const int i0 = blockIdx.x * 64;
    const int hoff = offs[e];
    const int tid = threadIdx.x;

    __shared__ __align__(16) bf16 As[64 * 64];
    __shared__ __align__(16) bf16 Bs[128 * 64];
    __shared__ int toks[64];

    if (tid < 64) {
        int r = row0 + tid; if (r >= count) r = count - 1;
        toks[tid] = tok_list[e * T_TOK + r];
    }
    __syncthreads();

    const int lane = tid & 63, wid = tid >> 6;
    const int la = lane & 15, lq = lane >> 4;
    const int wm = wid >> 1, wn = wid & 1;

    // A staging: 512 chunks, 2 per thread
    int ra0 = tid >> 3, s0 = tid & 7;
    int ca0 = s0 ^ (ra0 & 7);
    int ra1 = ra0 + 32;
    int ca1 = s0 ^ (ra1 & 7);
    const bf16* srcA0 = xb + (size_t)toks[ra0] * H_DIM + ca0 * 8;
    const bf16* srcA1 = xb + (size_t)toks[ra1] * H_DIM + ca1 * 8;
    bf16* dstA0 = As + (size_t)(wid * 64) * 8;
    bf16* dstA1 = As + (size_t)(wid * 64 + 256) * 8;

    // B staging: 1024 chunks, 4 per thread; rows interleaved 32g/32u
    const bf16* srcB[4]; bf16* dstB[4];
#pragma unroll
    for (int i = 0; i < 4; ++i) {
        int idx = tid + 256 * i;
        int r = idx >> 3, s = idx & 7;
        int c8 = s ^ (r & 7);
        int is_u = (r >> 5) & 1;
        int ioff = (r >> 6) * 32 + (r & 31);
        size_t grow = (size_t)e * (2 * I_DIM) + (size_t)is_u * I_DIM + i0 + ioff;
        srcB[i] = gub + grow * H_DIM + c8 * 8;
        dstB[i] = Bs + (size_t)(256 * i + wid * 64) * 8;
    }

    f32x4 acc[2][4];
#pragma unroll
    for (int a = 0; a < 2; ++a)
#pragma unroll
        for (int b = 0; b < 4; ++b) acc[a][b] = (f32x4){0.f, 0.f, 0.f, 0.f};

    for (int k0 = 0; k0 < H_DIM; k0 += 64) {
        async_cp16(dstA0, srcA0 + k0);
        async_cp16(dstA1, srcA1 + k0);
#pragma unroll
        for (int i = 0; i < 4; ++i) async_cp16(dstB[i], srcB[i] + k0);
        __syncthreads();
#pragma unroll
        for (int ks = 0; ks < 2; ++ks) {
            bf16x8 af[2], bfr[4];
            int ch = lq + 4 * ks;
#pragma unroll
            for (int mt = 0; mt < 2; ++mt) {
                int row = 32 * wm + 16 * mt + la;
                int sl = ch ^ (row & 7);
                af[mt] = *(const bf16x8*)(As + (size_t)(row * 8 + sl) * 8);
            }
#pragma unroll
            for (int nt = 0; nt < 4; ++nt) {
                int row = 64 * wn + 16 * nt + la;
                int sl = ch ^ (row & 7);
                bfr[nt] = *(const bf16x8*)(Bs + (size_t)(row * 8 + sl) * 8);
            }
#pragma unroll
            for (int mt = 0; mt < 2; ++mt)
#pragma unroll
                for (int nt = 0; nt < 4; ++nt)
                    acc[mt][nt] = __builtin_amdgcn_mfma_f32_16x16x32_bf16(af[mt], bfr[nt], acc[mt][nt], 0, 0, 0);
        }
        __syncthreads();
    }

    // epilogue: nt {0,1} = g, nt {2,3} = u for the same i-range
#pragma unroll
    for (int mt = 0; mt < 2; ++mt)
#pragma unroll
        for (int p = 0; p < 2; ++p)
#pragma unroll
            for (int r = 0; r < 4; ++r) {
                int trow = 32 * wm + 16 * mt + lq * 4 + r;
                if (row0 + trow < count) {
                    float g = acc[mt][p][r], u = acc[mt][p + 2][r];
                    float hv = (g / (1.0f + __expf(-g))) * u;
                    int col = i0 + 32 * wn + 16 * p + la;
                    hbuf[(size_t)(hoff + row0 + trow) * I_DIM + col] = (bf16)hv;
                }
            }
}

// ---------------- Grouped down GEMM + weighted scatter -----------------------
// Tile: M=64 tokens x N=128 H-cols, K=768.
__global__ __launch_bounds__(256, 4) void down_kernel(
    const bf16* __restrict__ dwb, const bf16* __restrict__ hbuf,
    const int* __restrict__ cnt, const int* __restrict__ offs,
    const int* __restrict__ tok_list, const float* __restrict__ wgt_list,
    float* __restrict__ out)
{
    const int e = blockIdx.z;
    const int count = cnt[e];
    const int row0 = blockIdx.y * 64;
    if (row0 >= count) return;
    const int n0 = blockIdx.x * 128;
    const int hoff = offs[e];
    const int tid = threadIdx.x;

    __shared__ __align__(16) bf16 As[64 * 64];
    __shared__ __align__(16) bf16 Bs[128 * 64];
    __shared__ int toks[64];
    __shared__ float wgts[64];

    if (tid < 64) {
        int r = row0 + tid; if (r >= count) r = count - 1;
        toks[tid] = tok_list[e * T_TOK + r];
        wgts[tid] = wgt_list[e * T_TOK + r];
    }
    __syncthreads();

    const int lane = tid & 63, wid = tid >> 6;
    const int la = lane & 15, lq = lane >> 4;
    const int wm = wid >> 1, wn = wid & 1;

    int ra0 = tid >> 3, s0 = tid & 7;
    int ca0 = s0 ^ (ra0 & 7);
    int ra1 = ra0 + 32;
    int ca1 = s0 ^ (ra1 & 7);
    int ar0 = row0 + ra0; if (ar0 >= count) ar0 = count - 1;
    int ar1 = row0 + ra1; if (ar1 >= count) ar1 = count - 1;
    const bf16* srcA0 = hbuf + (size_t)(hoff + ar0) * I_DIM + ca0 * 8;
    const bf16* srcA1 = hbuf + (size_t)(hoff + ar1) * I_DIM + ca1 * 8;
    bf16* dstA0 = As + (size_t)(wid * 64) * 8;
    bf16* dstA1 = As + (size_t)(wid * 64 + 256) * 8;

    const bf16* srcB[4]; bf16* dstB[4];
#pragma unroll
    for (int i = 0; i < 4; ++i) {
        int idx = tid + 256 * i;
        int r = idx >> 3, s = idx & 7;
        int c8 = s ^ (r & 7);
        srcB[i] = dwb + ((size_t)e * H_DIM + n0 + r) * I_DIM + c8 * 8;
        dstB[i] = Bs + (size_t)(256 * i + wid * 64) * 8;
    }

    f32x4 acc[2][4];
#pragma unroll
    for (int a = 0; a < 2; ++a)
#pragma unroll
        for (int b = 0; b < 4; ++b) acc[a][b] = (f32x4){0.f, 0.f, 0.f, 0.f};

    for (int k0 = 0; k0 < I_DIM; k0 += 64) {
        async_cp16(dstA0, srcA0 + k0);
        async_cp16(dstA1, srcA1 + k0);
#pragma unroll
        for (int i = 0; i < 4; ++i) async_cp16(dstB[i], srcB[i] + k0);
        __syncthreads();
#pragma unroll
        for (int ks = 0; ks < 2; ++ks) {
            bf16x8 af[2], bfr[4];
            int ch = lq + 4 * ks;
#pragma unroll
            for (int mt = 0; mt < 2; ++mt) {
                int row = 32 * wm + 16 * mt + la;
                int sl = ch ^ (row & 7);
                af[mt] = *(const bf16x8*)(As + (size_t)(row * 8 + sl) * 8);
            }
#pragma unroll
            for (int nt = 0; nt < 4; ++nt) {
                int row = 64 * wn + 16 * nt + la;
                int sl = ch ^ (row & 7);
                bfr[nt] = *(const bf16x8*)(Bs + (size_t)(row * 8 + sl) * 8);
            }
#pragma unroll
            for (int mt = 0; mt < 2; ++mt)
#pragma unroll
                for (int nt = 0; nt < 4; ++nt)
                    acc[mt][nt] = __builtin_amdgcn_mfma_f32_16x16x32_bf16(af[mt], bfr[nt], acc[mt][nt], 0, 0, 0);
        }
        __syncthreads();
    }

#pragma unroll
    for (int mt = 0; mt < 2; ++mt)
#pragma unroll
        for (int nt = 0; nt < 4; ++nt)
#pragma unroll
            for (int r = 0; r < 4; ++r) {
                int trow = 32 * wm + 16 * mt + lq * 4 + r;
                if (row0 + trow < count) {
                    int col = n0 + 64 * wn + 16 * nt + la;
                    atomicAdd(&out[(size_t)toks[trow] * H_DIM + col],
                              wgts[trow] * acc[mt][nt][r]);
                }
            }
}

// ---------------- Launch -----------------------------------------------------
extern "C" void kernel_launch(void* const* d_in, const int* in_sizes, int n_in,
                              void* d_out, int out_size, void* d_ws, size_t ws_size,
                              hipStream_t stream)
{
    const float* x   = (const float*)d_in[0];
    const float* gw  = (const float*)d_in[1];
    const float* gup = (const float*)d_in[2];
    const float* dw  = (const float*)d_in[3];
    float* out = (float*)d_out;
    float* logits = out + (size_t)T_TOK * H_DIM;

    char* ws = (char*)d_ws;
    int*   cnt      = (int*)(ws + 0);
    int*   offs     = (int*)(ws + 256);
    int*   tok_list = (int*)(ws + 512);                 // 128 KiB
    float* wgt_list = (float*)(ws + 131584);            // 128 KiB
    bf16*  hbuf     = (bf16*)(ws + 262656);             // 6 MiB
    bf16*  xb       = (bf16*)(ws + 6554112);            // 8 MiB
    bf16*  gub      = (bf16*)(ws + 14942720);           // 96 MiB
    bf16*  dwb      = (bf16*)(ws + 115606016);          // 48 MiB  (end ~158.3 MiB)

    hipMemsetAsync(cnt, 0, 256, stream);
    hipMemsetAsync(out, 0, (size_t)T_TOK * H_DIM * sizeof(float), stream);

    convert_kernel<<<4096, 256, 0, stream>>>(gup, dw, gub, dwb);
    router_kernel<<<T_TOK, 256, 0, stream>>>(x, gw, logits, cnt, tok_list, wgt_list, xb);
    scan_kernel<<<1, 64, 0, stream>>>(cnt, offs);
    gateup_kernel<<<dim3(I_DIM / 64, T_TOK / 64, E_NUM), 256, 0, stream>>>(
        xb, gub, cnt, offs, tok_list, hbuf);
    down_kernel<<<dim3(H_DIM / 128, T_TOK / 64, E_NUM), 256, 0, stream>>>(
        dwb, hbuf, cnt, offs, tok_list, wgt_list, out);
}

// Round 3
// 529.799 us; speedup vs baseline: 1.2329x; 1.0485x over previous
//
#include <hip/hip_runtime.h>
#include <hip/hip_bf16.h>
#include <stdint.h>

#define T_TOK 2048
#define H_DIM 2048
#define E_NUM 16
#define I_DIM 768

typedef __bf16 bf16;
typedef __bf16 bf16x4 __attribute__((ext_vector_type(4)));
typedef __bf16 bf16x8 __attribute__((ext_vector_type(8)));
typedef float f32x4 __attribute__((ext_vector_type(4)));

__device__ __forceinline__ void async_cp16(void* l, const void* g) {
    __builtin_amdgcn_global_load_lds(
        (const __attribute__((address_space(1))) void*)g,
        (__attribute__((address_space(3))) void*)l, 16, 0, 0);
}

// ---------------- Router: fp64 logits, shuffle reduce, top-2, x->bf16 --------
__global__ __launch_bounds__(256) void router_kernel(
    const float* __restrict__ x, const float* __restrict__ gw,
    float* __restrict__ logits, int* __restrict__ cnt,
    int* __restrict__ tok_list, float* __restrict__ wgt_list,
    bf16* __restrict__ xb)
{
    const int t = blockIdx.x;
    const int tid = threadIdx.x;
    const int lane = tid & 63, wid = tid >> 6;

    double part[E_NUM];
#pragma unroll
    for (int e = 0; e < E_NUM; ++e) part[e] = 0.0;

#pragma unroll
    for (int it = 0; it < 2; ++it) {
        int h = it * 1024 + tid * 4;
        float4 xv = *(const float4*)(x + (size_t)t * H_DIM + h);
        bf16x4 xb4 = { (bf16)xv.x, (bf16)xv.y, (bf16)xv.z, (bf16)xv.w };
        *(bf16x4*)(xb + (size_t)t * H_DIM + h) = xb4;
#pragma unroll
        for (int e = 0; e < E_NUM; ++e) {
            float4 wv = *(const float4*)(gw + (size_t)e * H_DIM + h);
            part[e] += (double)xv.x * (double)wv.x + (double)xv.y * (double)wv.y
                     + (double)xv.z * (double)wv.z + (double)xv.w * (double)wv.w;
        }
    }
    // wave-level butterfly
#pragma unroll
    for (int off = 32; off > 0; off >>= 1)
#pragma unroll
        for (int e = 0; e < E_NUM; ++e)
            part[e] += __shfl_down(part[e], off);

    __shared__ double sh[4][E_NUM];
    __shared__ float lg[E_NUM];
    if (lane == 0)
#pragma unroll
        for (int e = 0; e < E_NUM; ++e) sh[wid][e] = part[e];
    __syncthreads();
    if (tid < E_NUM) {
        float v = (float)(sh[0][tid] + sh[1][tid] + sh[2][tid] + sh[3][tid]);
        lg[tid] = v;
        logits[(size_t)t * E_NUM + tid] = v;
    }
    __syncthreads();
    if (tid == 0) {
        int i0 = 0; float v0 = lg[0];
#pragma unroll
        for (int e = 1; e < E_NUM; ++e) if (lg[e] > v0) { v0 = lg[e]; i0 = e; }
        int i1 = -1; float v1 = -3.4e38f;
#pragma unroll
        for (int e = 0; e < E_NUM; ++e) if (e != i0 && lg[e] > v1) { v1 = lg[e]; i1 = e; }
        float w0 = 1.0f / (1.0f + __expf(v1 - v0));
        float w1 = 1.0f - w0;
        int p0 = atomicAdd(&cnt[i0], 1);
        tok_list[i0 * T_TOK + p0] = t; wgt_list[i0 * T_TOK + p0] = w0;
        int p1 = atomicAdd(&cnt[i1], 1);
        tok_list[i1 * T_TOK + p1] = t; wgt_list[i1 * T_TOK + p1] = w1;
    }
}

// ---------------- Offsets scan (16 values) ----------------------------------
__global__ void scan_kernel(const int* __restrict__ cnt, int* __restrict__ offs)
{
    if (threadIdx.x == 0) {
        int o = 0;
        for (int e = 0; e < E_NUM; ++e) { offs[e] = o; o += cnt[e]; }
    }
}

// ---------------- Grouped gate_up GEMM + SwiGLU ------------------------------
// M=64 tokens x 64 i-cols. A: bf16 (xb). B: fp32 weights staged raw into LDS,
// converted to bf16 at fragment build. XOR-swizzled 16B chunks.
__global__ __launch_bounds__(256, 4) void gateup_kernel(
    const bf16* __restrict__ xb, const float* __restrict__ gup,
    const int* __restrict__ cnt, const int* __restrict__ offs,
    const int* __restrict__ tok_list, bf16* __restrict__ hbuf)
{
    const int e = blockIdx.z;
    const int count = cnt[e];
    const int row0 = blockIdx.y * 64;
    if (row0 >= count) return;
    const int i0 = blockIdx.x * 64;
    const int hoff = offs[e];
    const int tid = threadIdx.x;
    const int lane = tid & 63, wid = tid >> 6;

    __shared__ __align__(16) bf16 As[64 * 64];     // 8 KB
    __shared__ __align__(16) float Bs[128 * 64];   // 32 KB

    // ---- A staging (bf16, 8-chunk rows, mask &7): 2 chunks/thread
    int raA0 = tid >> 3, sA0 = tid & 7;
    int raA1 = raA0 + 32;
    int cA0 = sA0 ^ (raA0 & 7);
    int cA1 = sA0 ^ (raA1 & 7);
    int tr0 = row0 + raA0; if (tr0 >= count) tr0 = count - 1;
    int tr1 = row0 + raA1; if (tr1 >= count) tr1 = count - 1;
    const bf16* srcA0 = xb + (size_t)tok_list[e * T_TOK + tr0] * H_DIM + cA0 * 8;
    const bf16* srcA1 = xb + (size_t)tok_list[e * T_TOK + tr1] * H_DIM + cA1 * 8;
    bf16* dstA0 = As + (size_t)(wid * 64) * 8;
    bf16* dstA1 = As + (size_t)(wid * 64 + 256) * 8;

    // ---- B staging (fp32, 16-chunk rows, mask &15): 8 chunks/thread
    const float* srcB[8]; float* dstB[8];
#pragma unroll
    for (int i = 0; i < 8; ++i) {
        int idx = i * 256 + tid;
        int r = idx >> 4, s = idx & 15;
        int c = s ^ (r & 15);
        int is_u = (r >> 5) & 1;
        int ioff = (r >> 6) * 32 + (r & 31);
        size_t grow = (size_t)e * (2 * I_DIM) + (size_t)is_u * I_DIM + i0 + ioff;
        srcB[i] = gup + grow * H_DIM + c * 4;
        dstB[i] = Bs + (size_t)(i * 256 + wid * 64) * 4;
    }

    f32x4 acc[2][4];
#pragma unroll
    for (int a = 0; a < 2; ++a)
#pragma unroll
        for (int b = 0; b < 4; ++b) acc[a][b] = (f32x4){0.f, 0.f, 0.f, 0.f};

    const int la = lane & 15, lq = lane >> 4;
    const int wm = wid >> 1, wn = wid & 1;

    for (int k0 = 0; k0 < H_DIM; k0 += 64) {
        async_cp16(dstA0, srcA0 + k0);
        async_cp16(dstA1, srcA1 + k0);
#pragma unroll
        for (int i = 0; i < 8; ++i) async_cp16(dstB[i], srcB[i] + k0);
        __syncthreads();
#pragma unroll
        for (int ks = 0; ks < 2; ++ks) {
            bf16x8 af[2], bfr[4];
            int chA = ks * 4 + lq;
            int c0 = ks * 8 + lq * 2;
#pragma unroll
            for (int mt = 0; mt < 2; ++mt) {
                int row = 32 * wm + 16 * mt + la;
                int sl = chA ^ (row & 7);
                af[mt] = *(const bf16x8*)(As + (size_t)(row * 8 + sl) * 8);
            }
#pragma unroll
            for (int nt = 0; nt < 4; ++nt) {
                int row = 64 * wn + 16 * nt + la;
                int s0 = c0 ^ (row & 15);
                int s1 = s0 ^ 1;
                f32x4 v0 = *(const f32x4*)(Bs + (size_t)(row * 16 + s0) * 4);
                f32x4 v1 = *(const f32x4*)(Bs + (size_t)(row * 16 + s1) * 4);
                bfr[nt] = (bf16x8){ (bf16)v0.x, (bf16)v0.y, (bf16)v0.z, (bf16)v0.w,
                                    (bf16)v1.x, (bf16)v1.y, (bf16)v1.z, (bf16)v1.w };
            }
#pragma unroll
            for (int mt = 0; mt < 2; ++mt)
#pragma unroll
                for (int nt = 0; nt < 4; ++nt)
                    acc[mt][nt] = __builtin_amdgcn_mfma_f32_16x16x32_bf16(af[mt], bfr[nt], acc[mt][nt], 0, 0, 0);
        }
        __syncthreads();
    }

    // epilogue: nt {0,1} = g, nt {2,3} = u for the same i-range
#pragma unroll
    for (int mt = 0; mt < 2; ++mt)
#pragma unroll
        for (int p = 0; p < 2; ++p)
#pragma unroll
            for (int r = 0; r < 4; ++r) {
                int trow = 32 * wm + 16 * mt + lq * 4 + r;
                if (row0 + trow < count) {
                    float g = acc[mt][p][r], u = acc[mt][p + 2][r];
                    float hv = (g / (1.0f + __expf(-g))) * u;
                    int col = i0 + 32 * wn + 16 * p + la;
                    hbuf[(size_t)(hoff + row0 + trow) * I_DIM + col] = (bf16)hv;
                }
            }
}

// ---------------- Grouped down GEMM + weighted scatter -----------------------
// M=64 tokens x N=128 H-cols, K=768. B = fp32 down weights, staged raw.
__global__ __launch_bounds__(256, 4) void down_kernel(
    const float* __restrict__ dw, const bf16* __restrict__ hbuf,
    const int* __restrict__ cnt, const int* __restrict__ offs,
    const int* __restrict__ tok_list, const float* __restrict__ wgt_list,
    float* __restrict__ out)
{
    const int e = blockIdx.z;
    const int count = cnt[e];
    const int row0 = blockIdx.y * 64;
    if (row0 >= count) return;
    const int n0 = blockIdx.x * 128;
    const int hoff = offs[e];
    const int tid = threadIdx.x;
    const int lane = tid & 63, wid = tid >> 6;

    __shared__ __align__(16) bf16 As[64 * 64];     // 8 KB
    __shared__ __align__(16) float Bs[128 * 64];   // 32 KB

    int raA0 = tid >> 3, sA0 = tid & 7;
    int raA1 = raA0 + 32;
    int cA0 = sA0 ^ (raA0 & 7);
    int cA1 = sA0 ^ (raA1 & 7);
    int ar0 = row0 + raA0; if (ar0 >= count) ar0 = count - 1;
    int ar1 = row0 + raA1; if (ar1 >= count) ar1 = count - 1;
    const bf16* srcA0 = hbuf + (size_t)(hoff + ar0) * I_DIM + cA0 * 8;
    const bf16* srcA1 = hbuf + (size_t)(hoff + ar1) * I_DIM + cA1 * 8;
    bf16* dstA0 = As + (size_t)(wid * 64) * 8;
    bf16* dstA1 = As + (size_t)(wid * 64 + 256) * 8;

    const float* srcB[8]; float* dstB[8];
#pragma unroll
    for (int i = 0; i < 8; ++i) {
        int idx = i * 256 + tid;
        int r = idx >> 4, s = idx & 15;
        int c = s ^ (r & 15);
        srcB[i] = dw + ((size_t)e * H_DIM + n0 + r) * I_DIM + c * 4;
        dstB[i] = Bs + (size_t)(i * 256 + wid * 64) * 4;
    }

    f32x4 acc[2][4];
#pragma unroll
    for (int a = 0; a < 2; ++a)
#pragma unroll
        for (int b = 0; b < 4; ++b) acc[a][b] = (f32x4){0.f, 0.f, 0.f, 0.f};

    const int la = lane & 15, lq = lane >> 4;
    const int wm = wid >> 1, wn = wid & 1;

    for (int k0 = 0; k0 < I_DIM; k0 += 64) {
        async_cp16(dstA0, srcA0 + k0);
        async_cp16(dstA1, srcA1 + k0);
#pragma unroll
        for (int i = 0; i < 8; ++i) async_cp16(dstB[i], srcB[i] + k0);
        __syncthreads();
#pragma unroll
        for (int ks = 0; ks < 2; ++ks) {
            bf16x8 af[2], bfr[4];
            int chA = ks * 4 + lq;
            int c0 = ks * 8 + lq * 2;
#pragma unroll
            for (int mt = 0; mt < 2; ++mt) {
                int row = 32 * wm + 16 * mt + la;
                int sl = chA ^ (row & 7);
                af[mt] = *(const bf16x8*)(As + (size_t)(row * 8 + sl) * 8);
            }
#pragma unroll
            for (int nt = 0; nt < 4; ++nt) {
                int row = 64 * wn + 16 * nt + la;
                int s0 = c0 ^ (row & 15);
                int s1 = s0 ^ 1;
                f32x4 v0 = *(const f32x4*)(Bs + (size_t)(row * 16 + s0) * 4);
                f32x4 v1 = *(const f32x4*)(Bs + (size_t)(row * 16 + s1) * 4);
                bfr[nt] = (bf16x8){ (bf16)v0.x, (bf16)v0.y, (bf16)v0.z, (bf16)v0.w,
                                    (bf16)v1.x, (bf16)v1.y, (bf16)v1.z, (bf16)v1.w };
            }
#pragma unroll
            for (int mt = 0; mt < 2; ++mt)
#pragma unroll
                for (int nt = 0; nt < 4; ++nt)
                    acc[mt][nt] = __builtin_amdgcn_mfma_f32_16x16x32_bf16(af[mt], bfr[nt], acc[mt][nt], 0, 0, 0);
        }
        __syncthreads();
    }

#pragma unroll
    for (int mt = 0; mt < 2; ++mt)
#pragma unroll
        for (int nt = 0; nt < 4; ++nt)
#pragma unroll
            for (int r = 0; r < 4; ++r) {
                int trow = 32 * wm + 16 * mt + lq * 4 + r;
                if (row0 + trow < count) {
                    int col = n0 + 64 * wn + 16 * nt + la;
                    int grow = row0 + trow;
                    atomicAdd(&out[(size_t)tok_list[e * T_TOK + grow] * H_DIM + col],
                              wgt_list[e * T_TOK + grow] * acc[mt][nt][r]);
                }
            }
}

// ---------------- Launch -----------------------------------------------------
extern "C" void kernel_launch(void* const* d_in, const int* in_sizes, int n_in,
                              void* d_out, int out_size, void* d_ws, size_t ws_size,
                              hipStream_t stream)
{
    const float* x   = (const float*)d_in[0];
    const float* gw  = (const float*)d_in[1];
    const float* gup = (const float*)d_in[2];
    const float* dw  = (const float*)d_in[3];
    float* out = (float*)d_out;
    float* logits = out + (size_t)T_TOK * H_DIM;

    char* ws = (char*)d_ws;
    int*   cnt      = (int*)(ws + 0);
    int*   offs     = (int*)(ws + 256);
    int*   tok_list = (int*)(ws + 512);                 // 128 KiB
    float* wgt_list = (float*)(ws + 131584);            // 128 KiB
    bf16*  hbuf     = (bf16*)(ws + 262656);             // 6 MiB
    bf16*  xb       = (bf16*)(ws + 6554112);            // 8 MiB (end ~14.3 MiB)

    hipMemsetAsync(cnt, 0, 256, stream);
    hipMemsetAsync(out, 0, (size_t)T_TOK * H_DIM * sizeof(float), stream);

    router_kernel<<<T_TOK, 256, 0, stream>>>(x, gw, logits, cnt, tok_list, wgt_list, xb);
    scan_kernel<<<1, 64, 0, stream>>>(cnt, offs);
    gateup_kernel<<<dim3(I_DIM / 64, T_TOK / 64, E_NUM), 256, 0, stream>>>(
        xb, gup, cnt, offs, tok_list, hbuf);
    down_kernel<<<dim3(H_DIM / 128, T_TOK / 64, E_NUM), 256, 0, stream>>>(
        dw, hbuf, cnt, offs, tok_list, wgt_list, out);
}